// Round 17
// baseline (945.543 us; speedup 1.0000x reference)
//
#include <hip/hip_runtime.h>
#include <hip/hip_bf16.h>
#include <math.h>

#define NN 10000
#define NE 160000
#define NG 64
#define NT 5
#define NL 4
#define ADL 2.833213344056216f

// ws layout (float offsets)
#define OFF_H      0
#define OFF_HC     750000
#define OFF_P      1500000     // bf16 P during agg; reused as bf16 post partials z=0..6
#define OFF_Q      5250000     // bf16 Q
#define OFF_AGG    9000000     // bf16 agg
#define OFF_RLUT   24000000
#define OFF_INVDEG 24006000
#define OFF_AMP    24016000
#define OFF_ATT    24026000
#define OFF_STATS  24036000    // 2 ping-pong buffers x 192 floats
#define OFF_GPOOL  24040000
#define OFF_INT    24118960

__device__ __forceinline__ float bf2f(__hip_bfloat16 v){ return __bfloat162float(v); }

__global__ void k_zero_cnt(int* cnt){
    int i = blockIdx.x*256 + threadIdx.x;
    if (i < NN) cnt[i] = 0;
}

// h0 = node_emb[x].reshape(N,150) @ pre_lin_W + b
__global__ __launch_bounds__(256) void k_h0(const int* __restrict__ x,
        const float* __restrict__ node_emb, const float* __restrict__ plW,
        const float* __restrict__ plb, float* __restrict__ h){
    __shared__ float s_emb[21*75];
    __shared__ float s_W[150*75];
    __shared__ float s_b[75];
    int tid = threadIdx.x;
    for (int i = tid; i < 21*75; i += 256) s_emb[i] = node_emb[i];
    for (int i = tid; i < 150*75; i += 256) s_W[i] = plW[i];
    if (tid < 75) s_b[tid] = plb[tid];
    __syncthreads();
    for (int out = blockIdx.x*256 + tid; out < NN*75; out += gridDim.x*256){
        int n = out / 75, f = out - n*75;
        int x0 = x[2*n], x1 = x[2*n+1];
        float acc = s_b[f];
        const float* e0 = s_emb + x0*75;
        const float* e1 = s_emb + x1*75;
        #pragma unroll 5
        for (int k = 0; k < 75; k++)
            acc += e0[k]*s_W[k*75+f] + e1[k]*s_W[(75+k)*75+f];
        h[out] = acc;
    }
}

__global__ void k_hist(const int* __restrict__ ei, int* __restrict__ cnt){
    int e = blockIdx.x*256 + threadIdx.x;
    if (e < NE) atomicAdd(&cnt[ei[NE + e]], 1);
}

// single-block prefix sum: eoff[0]=0, eoff[n+1]=inclusive prefix
__global__ void k_scan(const int* __restrict__ cnt, int* __restrict__ eoff){
    __shared__ int buf[256];
    __shared__ int carry;
    int tid = threadIdx.x;
    if (tid == 0){ carry = 0; eoff[0] = 0; }
    __syncthreads();
    for (int base = 0; base < NN; base += 256){
        int v = (base + tid < NN) ? cnt[base + tid] : 0;
        buf[tid] = v; __syncthreads();
        for (int off = 1; off < 256; off <<= 1){
            int t2 = (tid >= off) ? buf[tid - off] : 0;
            __syncthreads();
            buf[tid] += t2;
            __syncthreads();
        }
        int inc = buf[tid] + carry;
        if (base + tid < NN) eoff[base + tid + 1] = inc;
        __syncthreads();
        if (tid == 255) carry = inc;
        __syncthreads();
    }
}

__global__ void k_nodestats(const int* __restrict__ cnt, const int* __restrict__ eoff,
        float* __restrict__ invdeg, float* __restrict__ amp, float* __restrict__ att,
        int* __restrict__ cursor){
    int n = blockIdx.x*256 + threadIdx.x;
    if (n >= NN) return;
    int c = cnt[n];
    cursor[n] = eoff[n];
    float cf = (float)c;
    float dg = cf < 1.f ? 1.f : cf;
    invdeg[n] = 1.f / dg;
    float ld = logf(dg + 1.f);
    amp[n] = ld / ADL;
    att[n] = ADL / ld;
}

__global__ void k_scatter(const int* __restrict__ ei, const int* __restrict__ ea,
        int* __restrict__ cursor, int* __restrict__ esrc, int* __restrict__ ecombo){
    int e = blockIdx.x*256 + threadIdx.x;
    if (e >= NE) return;
    int src = ei[e], dst = ei[NE + e];
    int pos = atomicAdd(&cursor[dst], 1);
    esrc[pos] = src;
    ecombo[pos] = ea[2*e]*4 + ea[2*e+1];
}

// Fused kernel, grid 319 x 384:
//  bx <  313 : P/Q (32 nodes/block, bf16). For l>0, the h-staging applies the
//              PREVIOUS layer's BN+ReLU inline (reads hc + stats ping-pong
//              buffer (l-1)&1) and writes h out — replaces k_bnapply launches.
//  bx 313-317: Rlut for tower t = bx-313
//  bx == 318 : zero stats buffer l&1 (this layer's k_lin accumulator; the
//              buffer read above is (l-1)&1 — no race)
__global__ __launch_bounds__(384) void k_pq(float* __restrict__ h,
        const float* __restrict__ hc, const float* __restrict__ bng,
        const float* __restrict__ bnb,
        const float* __restrict__ preW, const float* __restrict__ preb,
        const float* __restrict__ edge_emb, const float* __restrict__ encW,
        const float* __restrict__ encb, int l,
        __hip_bfloat16* __restrict__ P, __hip_bfloat16* __restrict__ Q,
        float* __restrict__ Rlut, float* __restrict__ stats_all){
    __shared__ float smem[10675];
    int tid = threadIdx.x;
    int bx = blockIdx.x;

    if (bx == 318){
        float* stats_wr = stats_all + (l & 1)*192;
        for (int i = tid; i < 150; i += 384) stats_wr[i] = 0.f;
        return;
    }
    if (bx >= 313){
        // ---- Rlut for tower t ----
        int t = bx - 313;
        float* s_encW = smem;            // 50*75 = 3750
        float* s_ev   = smem + 3750;     // 16*75 = 1200
        float* s_wc   = smem + 4950;     // 75*75 = 5625
        float* s_ee   = smem + 10575;    // 100
        for (int i = tid; i < 3750; i += 384) s_encW[i] = encW[(size_t)l*3750 + i];
        for (int i = tid; i < 100; i += 384) s_ee[i] = edge_emb[i];
        const float* wcsrc = preW + (((size_t)(l*NT + t))*225 + 150)*75;
        for (int i = tid; i < 5625; i += 384) s_wc[i] = wcsrc[i];
        __syncthreads();
        for (int task = tid; task < 1200; task += 384){
            int b = task/75, m = task - 75*b;
            int a0 = b >> 2, a1 = b & 3;
            float s = encb[l*75 + m];
            for (int k = 0; k < 25; k++)
                s += s_ee[a0*25+k]*s_encW[k*75+m] + s_ee[a1*25+k]*s_encW[(25+k)*75+m];
            s_ev[task] = s;
        }
        __syncthreads();
        for (int task = tid; task < 1200; task += 384){
            int b = task/75, f = task - 75*b;
            float r = preb[((size_t)l*NT + t)*75 + f];
            const float* ev = s_ev + b*75;
            #pragma unroll 5
            for (int m = 0; m < 75; m++) r += ev[m]*s_wc[m*75 + f];
            Rlut[b*375 + t*75 + f] = r;
        }
        return;
    }

    // ---- P/Q (with inline BN+ReLU from previous layer when l>0) ----
    float* h_t = smem;   // 32*76 = 2432
    int base = bx*32;
    if (l == 0){
        for (int idx = tid; idx < 32*75; idx += 384){
            int i = idx/75, m = idx - 75*i;
            int n = base + i;
            h_t[i*76 + m] = (n < NN) ? h[(size_t)n*75 + m] : 0.f;
        }
    } else {
        const float* stats_rd = stats_all + ((l + 1) & 1)*192;
        int lp = l - 1;
        for (int idx = tid; idx < 32*75; idx += 384){
            int i = idx/75, m = idx - 75*i;
            int n = base + i;
            float v = 0.f;
            if (n < NN){
                float mu = stats_rd[m]*(1.0f/NN);
                float var = stats_rd[75+m]*(1.0f/NN) - mu*mu;
                float inv = rsqrtf(var + 1e-5f);
                v = (hc[(size_t)n*75 + m] - mu)*inv*bng[lp*75+m] + bnb[lp*75+m];
                v = v > 0.f ? v : 0.f;
                h[(size_t)n*75 + m] = v;
            }
            h_t[i*76 + m] = v;
        }
    }
    __syncthreads();
    int j = tid;
    if (j >= 375) return;
    int t = j/75, f = j - 75*t;
    const float* wbase = preW + ((size_t)(l*NT + t))*225*75 + f;
    float accP[32], accQ[32];
    #pragma unroll
    for (int i = 0; i < 32; i++){ accP[i] = 0.f; accQ[i] = 0.f; }
    for (int m = 0; m < 72; m += 4){
        float wa0 = wbase[(m+0)*75], wa1 = wbase[(m+1)*75];
        float wa2 = wbase[(m+2)*75], wa3 = wbase[(m+3)*75];
        float wb0 = wbase[(75+m+0)*75], wb1 = wbase[(75+m+1)*75];
        float wb2 = wbase[(75+m+2)*75], wb3 = wbase[(75+m+3)*75];
        #pragma unroll
        for (int i = 0; i < 32; i++){
            const float4 hv = *(const float4*)&h_t[i*76 + m];
            accP[i] += hv.x*wa0 + hv.y*wa1 + hv.z*wa2 + hv.w*wa3;
            accQ[i] += hv.x*wb0 + hv.y*wb1 + hv.z*wb2 + hv.w*wb3;
        }
    }
    for (int m = 72; m < 75; m++){
        float wa = wbase[m*75], wb = wbase[(75+m)*75];
        #pragma unroll
        for (int i = 0; i < 32; i++){
            float v = h_t[i*76 + m];
            accP[i] += v*wa; accQ[i] += v*wb;
        }
    }
    for (int i = 0; i < 32; i++){
        int n = base + i;
        if (n < NN){
            P[(size_t)n*375 + j] = __float2bfloat16(accP[i]);
            Q[(size_t)n*375 + j] = __float2bfloat16(accQ[i]);
        }
    }
}

// grid (6, NN), block 64. bf16 Q gather; edge loop unrolled x8.
__global__ __launch_bounds__(64) void k_agg(const __hip_bfloat16* __restrict__ P,
        const __hip_bfloat16* __restrict__ Q, const float* __restrict__ Rlut,
        const int* __restrict__ eoff, const int* __restrict__ esrc,
        const int* __restrict__ ecombo, const float* __restrict__ invdeg,
        __hip_bfloat16* __restrict__ agg){
    int n = blockIdx.y;
    int j = blockIdx.x*64 + threadIdx.x;
    if (j >= 375) return;
    int lo = eoff[n], hi = eoff[n+1];
    float p = bf2f(P[(size_t)n*375 + j]);
    float sum = 0.f, sq = 0.f, mn = 3.4e38f, mx = -3.4e38f;
    int e = lo;
    for (; e + 8 <= hi; e += 8){
        int s0 = esrc[e],   s1 = esrc[e+1], s2 = esrc[e+2], s3 = esrc[e+3];
        int s4 = esrc[e+4], s5 = esrc[e+5], s6 = esrc[e+6], s7 = esrc[e+7];
        int c0 = ecombo[e],   c1 = ecombo[e+1], c2 = ecombo[e+2], c3 = ecombo[e+3];
        int c4 = ecombo[e+4], c5 = ecombo[e+5], c6 = ecombo[e+6], c7 = ecombo[e+7];
        float q0 = bf2f(Q[(size_t)s0*375 + j]);
        float q1 = bf2f(Q[(size_t)s1*375 + j]);
        float q2 = bf2f(Q[(size_t)s2*375 + j]);
        float q3 = bf2f(Q[(size_t)s3*375 + j]);
        float q4 = bf2f(Q[(size_t)s4*375 + j]);
        float q5 = bf2f(Q[(size_t)s5*375 + j]);
        float q6 = bf2f(Q[(size_t)s6*375 + j]);
        float q7 = bf2f(Q[(size_t)s7*375 + j]);
        float r0 = Rlut[c0*375 + j], r1 = Rlut[c1*375 + j];
        float r2 = Rlut[c2*375 + j], r3 = Rlut[c3*375 + j];
        float r4 = Rlut[c4*375 + j], r5 = Rlut[c5*375 + j];
        float r6 = Rlut[c6*375 + j], r7 = Rlut[c7*375 + j];
        float m0 = p + q0 + r0, m1 = p + q1 + r1;
        float m2 = p + q2 + r2, m3 = p + q3 + r3;
        float m4 = p + q4 + r4, m5 = p + q5 + r5;
        float m6 = p + q6 + r6, m7 = p + q7 + r7;
        sum += (m0 + m1 + m2 + m3) + (m4 + m5 + m6 + m7);
        sq  += (m0*m0 + m1*m1 + m2*m2 + m3*m3) + (m4*m4 + m5*m5 + m6*m6 + m7*m7);
        mn = fminf(mn, fminf(fminf(fminf(m0,m1), fminf(m2,m3)),
                             fminf(fminf(m4,m5), fminf(m6,m7))));
        mx = fmaxf(mx, fmaxf(fmaxf(fmaxf(m0,m1), fmaxf(m2,m3)),
                             fmaxf(fmaxf(m4,m5), fmaxf(m6,m7))));
    }
    for (; e < hi; e++){
        int s = esrc[e], cm = ecombo[e];
        float m = p + bf2f(Q[(size_t)s*375 + j]) + Rlut[cm*375 + j];
        sum += m; sq += m*m;
        mn = fminf(mn, m); mx = fmaxf(mx, m);
    }
    float id = invdeg[n];
    bool has = hi > lo;
    float mean = sum*id;
    float msq  = sq*id;
    float var = msq - mean*mean; var = var > 0.f ? var : 0.f;
    float sd = sqrtf(var + 1e-5f);
    float mnv = has ? mn : 0.f;
    float mxv = has ? mx : 0.f;
    int t = j/75, f = j - 75*t;
    __hip_bfloat16* a = agg + ((size_t)n*NT + t)*300;
    a[f]      = __float2bfloat16(mean);
    a[75+f]   = __float2bfloat16(mnv);
    a[150+f]  = __float2bfloat16(mxv);
    a[225+f]  = __float2bfloat16(sd);
}

// post einsum, barrier-free; bf16 partials. grid (40, 5, 7).
#define KB2 50
__global__ __launch_bounds__(256, 6) void k_post(const float* __restrict__ h,
        const __hip_bfloat16* __restrict__ agg, const float* __restrict__ postW,
        const float* __restrict__ postb, const float* __restrict__ amp,
        const float* __restrict__ att, int l, __hip_bfloat16* __restrict__ postbase){
    __shared__ float s_w[3*KB2*16];      // 9.6 KB (z0 uses first 75*16=1200)
    int t = blockIdx.y;
    int z = blockIdx.z;
    int nbase = blockIdx.x*256;
    int tid = threadIdx.x;
    int fg  = (tid & 3)*4;
    int sub = tid >> 2;
    const float* Wt = postW + ((size_t)(l*NT + t))*975*15;

    if (z == 0){
        for (int idx = tid; idx < 75*16; idx += 256){
            int c = idx >> 4, f = idx & 15;
            s_w[idx] = (f < 15) ? Wt[c*15 + f] : 0.f;
        }
        __syncthreads();
        float a1[4][4] = {};
        const float* hrow[4];
        #pragma unroll
        for (int j = 0; j < 4; j++){
            int n = nbase + sub + 64*j;
            hrow[j] = h + (size_t)(n < NN ? n : 0)*75;
        }
        #pragma unroll 3
        for (int k = 0; k < 75; k++){
            const float4 w1 = *(const float4*)&s_w[k*16 + fg];
            #pragma unroll
            for (int j = 0; j < 4; j++){
                float v = hrow[j][k];
                a1[j][0] += v*w1.x; a1[j][1] += v*w1.y;
                a1[j][2] += v*w1.z; a1[j][3] += v*w1.w;
            }
        }
        const float* pb = postb + (l*NT + t)*15;
        #pragma unroll
        for (int j = 0; j < 4; j++){
            int n = nbase + sub + 64*j;
            if (n >= NN) continue;
            __hip_bfloat16* dst = postbase + (size_t)n*75 + t*15;
            #pragma unroll
            for (int f = 0; f < 4; f++)
                if (fg + f < 15) dst[fg + f] = __float2bfloat16(a1[j][f] + pb[fg + f]);
        }
        return;
    }

    int kbeg = (z-1)*KB2;
    for (int idx = tid; idx < 3*KB2*16; idx += 256){
        int vrow = idx / (KB2*16);
        int rem = idx - vrow*(KB2*16);
        int c = rem >> 4, f = rem & 15;
        s_w[idx] = (f < 15) ? Wt[(75 + vrow*300 + kbeg + c)*15 + f] : 0.f;
    }
    __syncthreads();
    float a1[4][4] = {}, a2[4][4] = {}, a3[4][4] = {};
    const __hip_bfloat16* arow[4];
    #pragma unroll
    for (int j = 0; j < 4; j++){
        int n = nbase + sub + 64*j;
        arow[j] = agg + (size_t)(n < NN ? n : 0)*1500 + t*300 + kbeg;
    }
    #pragma unroll 2
    for (int k = 0; k < KB2; k++){
        const float4 w1 = *(const float4*)&s_w[k*16 + fg];
        const float4 w2 = *(const float4*)&s_w[(KB2 + k)*16 + fg];
        const float4 w3 = *(const float4*)&s_w[(2*KB2 + k)*16 + fg];
        #pragma unroll
        for (int j = 0; j < 4; j++){
            float v = bf2f(arow[j][k]);
            a1[j][0] += v*w1.x; a1[j][1] += v*w1.y;
            a1[j][2] += v*w1.z; a1[j][3] += v*w1.w;
            a2[j][0] += v*w2.x; a2[j][1] += v*w2.y;
            a2[j][2] += v*w2.z; a2[j][3] += v*w2.w;
            a3[j][0] += v*w3.x; a3[j][1] += v*w3.y;
            a3[j][2] += v*w3.z; a3[j][3] += v*w3.w;
        }
    }
    __hip_bfloat16* postv = postbase + (size_t)z*750000;
    #pragma unroll
    for (int j = 0; j < 4; j++){
        int n = nbase + sub + 64*j;
        if (n >= NN) continue;
        float am = amp[n], at = att[n];
        __hip_bfloat16* dst = postv + (size_t)n*75 + t*15;
        #pragma unroll
        for (int f = 0; f < 4; f++)
            if (fg + f < 15)
                dst[fg + f] = __float2bfloat16(a1[j][f] + am*a2[j][f] + at*a3[j][f]);
    }
}

// hc = (Σz postz) @ lin_W[l] + lin_b[l]; fused BN-stat reduction into buffer l&1.
// 64 nodes/block (157 blocks) to halve weight-staging traffic vs 32-node version.
__global__ __launch_bounds__(256) void k_lin(const __hip_bfloat16* __restrict__ postbase,
        const float* __restrict__ linW, const float* __restrict__ linb,
        int l, float* __restrict__ hc, float* __restrict__ stats_all){
    __shared__ float p_l[64*75];
    __shared__ float w_l[75*75];
    __shared__ float hc_l[64*75];
    int tid = threadIdx.x;
    int base = blockIdx.x*64;
    for (int i = tid; i < 75*75; i += 256) w_l[i] = linW[(size_t)l*5625 + i];
    for (int i = tid; i < 64*75; i += 256){
        int n = base + i/75;
        size_t idx = (size_t)base*75 + i;
        float v = 0.f;
        if (n < NN){
            #pragma unroll
            for (int z = 0; z < 7; z++) v += bf2f(postbase[idx + (size_t)z*750000]);
        }
        p_l[i] = v;
    }
    __syncthreads();
    for (int task = tid; task < 4800; task += 256){
        int i = task/75, o = task - 75*i;
        float s = linb[l*75 + o];
        const float* pl = p_l + i*75;
        #pragma unroll 5
        for (int j = 0; j < 75; j++) s += pl[j]*w_l[j*75 + o];
        hc_l[task] = s;
        if (base + i < NN) hc[(size_t)(base+i)*75 + o] = s;
    }
    __syncthreads();
    if (tid < 75){
        float* stats_wr = stats_all + (l & 1)*192;
        int nv = NN - base; if (nv > 64) nv = 64;
        float s1 = 0.f, s2 = 0.f;
        for (int i = 0; i < nv; i++){
            float v = hc_l[i*75 + tid];
            s1 += v; s2 += v*v;
        }
        atomicAdd(&stats_wr[tid], s1);
        atomicAdd(&stats_wr[75+tid], s2);
    }
}

// final BN apply (only after last layer; earlier layers fused into k_pq)
__global__ void k_bnapply(const float* __restrict__ hc, const float* __restrict__ stats,
        const float* __restrict__ bng, const float* __restrict__ bnb, int l,
        float* __restrict__ h){
    int idx = blockIdx.x*256 + threadIdx.x;
    if (idx >= NN*75) return;
    int col = idx % 75;
    float mu = stats[col]*(1.0f/NN);
    float var = stats[75+col]*(1.0f/NN) - mu*mu;
    float inv = rsqrtf(var + 1e-5f);
    float v = (hc[idx] - mu)*inv*bng[l*75+col] + bnb[l*75+col];
    h[idx] = v > 0.f ? v : 0.f;
}

__global__ __launch_bounds__(256) void k_pool(const float* __restrict__ h,
        const int* __restrict__ batch, float* __restrict__ gpool){
    int g = blockIdx.x, tid = threadIdx.x;
    int lo = 0, hi = NN;
    while (lo < hi){ int mid = (lo+hi)>>1; if (batch[mid] < g) lo = mid+1; else hi = mid; }
    int start = lo;
    lo = start; hi = NN;
    while (lo < hi){ int mid = (lo+hi)>>1; if (batch[mid] < g+1) lo = mid+1; else hi = mid; }
    int end = lo;
    __shared__ float red[225];
    if (tid < 225){
        int col = tid % 75, rep = tid / 75;
        float acc = 0.f;
        for (int i = start + rep; i < end; i += 3) acc += h[(size_t)i*75 + col];
        red[tid] = acc;
    }
    __syncthreads();
    if (tid < 75) gpool[g*75 + tid] = red[tid] + red[75+tid] + red[150+tid];
}

// 8 blocks x 8 graphs; weights in LDS, phase-parallel
__global__ __launch_bounds__(256) void k_mlp(const float* __restrict__ gpool,
        const float* __restrict__ W1, const float* __restrict__ b1,
        const float* __restrict__ W2, const float* __restrict__ b2,
        const float* __restrict__ W3, const float* __restrict__ b3,
        float* __restrict__ out){
    __shared__ float w1[75*50];
    __shared__ float w2[50*25];
    __shared__ float gp[8*75];
    __shared__ float t1[8*50];
    __shared__ float t2[8*25];
    int tid = threadIdx.x;
    int gbase = blockIdx.x*8;
    for (int i = tid; i < 75*50; i += 256) w1[i] = W1[i];
    for (int i = tid; i < 50*25; i += 256) w2[i] = W2[i];
    for (int i = tid; i < 8*75; i += 256) gp[i] = gpool[gbase*75 + i];
    __syncthreads();
    for (int task = tid; task < 8*50; task += 256){
        int g = task/50, j = task - 50*g;
        float s = b1[j];
        const float* gv = gp + g*75;
        #pragma unroll 5
        for (int k = 0; k < 75; k++) s += gv[k]*w1[k*50+j];
        t1[task] = s > 0.f ? s : 0.f;
    }
    __syncthreads();
    for (int task = tid; task < 8*25; task += 256){
        int g = task/25, j = task - 25*g;
        float s = b2[j];
        const float* tv = t1 + g*50;
        #pragma unroll 5
        for (int k = 0; k < 50; k++) s += tv[k]*w2[k*25+j];
        t2[task] = s > 0.f ? s : 0.f;
    }
    __syncthreads();
    if (tid < 8){
        float s = b3[0];
        const float* tv = t2 + tid*25;
        #pragma unroll
        for (int k = 0; k < 25; k++) s += tv[k]*W3[k];
        out[gbase + tid] = s;
    }
}

extern "C" void kernel_launch(void* const* d_in, const int* in_sizes, int n_in,
                              void* d_out, int out_size, void* d_ws, size_t ws_size,
                              hipStream_t stream){
    const int* x          = (const int*)d_in[0];
    const int* edge_index = (const int*)d_in[1];
    const int* edge_attr  = (const int*)d_in[2];
    const int* batch      = (const int*)d_in[3];
    const float* node_emb = (const float*)d_in[4];
    const float* edge_emb = (const float*)d_in[5];
    const float* pre_lin_W= (const float*)d_in[6];
    const float* pre_lin_b= (const float*)d_in[7];
    const float* encW     = (const float*)d_in[8];
    const float* encb     = (const float*)d_in[9];
    const float* preW     = (const float*)d_in[10];
    const float* preb     = (const float*)d_in[11];
    const float* postW    = (const float*)d_in[12];
    const float* postb    = (const float*)d_in[13];
    const float* linW     = (const float*)d_in[14];
    const float* linb     = (const float*)d_in[15];
    const float* bng      = (const float*)d_in[16];
    const float* bnb      = (const float*)d_in[17];
    const float* mlpW1    = (const float*)d_in[18];
    const float* mlpb1    = (const float*)d_in[19];
    const float* mlpW2    = (const float*)d_in[20];
    const float* mlpb2    = (const float*)d_in[21];
    const float* mlpW3    = (const float*)d_in[22];
    const float* mlpb3    = (const float*)d_in[23];

    float* ws = (float*)d_ws;
    float* h      = ws + OFF_H;
    float* hc     = ws + OFF_HC;
    __hip_bfloat16* P = (__hip_bfloat16*)(ws + OFF_P);
    __hip_bfloat16* Q = (__hip_bfloat16*)(ws + OFF_Q);
    __hip_bfloat16* agg = (__hip_bfloat16*)(ws + OFF_AGG);
    float* Rlut   = ws + OFF_RLUT;
    float* invdeg = ws + OFF_INVDEG;
    float* amp    = ws + OFF_AMP;
    float* att    = ws + OFF_ATT;
    float* stats  = ws + OFF_STATS;   // 2 x 192 ping-pong
    float* gpool  = ws + OFF_GPOOL;
    __hip_bfloat16* postbase = (__hip_bfloat16*)(ws + OFF_P);  // bf16 partials z=0..6
    int* iw     = (int*)(ws + OFF_INT);
    int* cnt    = iw;
    int* eoff   = cnt + NN;        // NN+1
    int* cursor = eoff + NN + 2;
    int* esrc   = cursor + NN;
    int* ecombo = esrc + NE;

    k_zero_cnt<<<40, 256, 0, stream>>>(cnt);
    k_h0<<<640, 256, 0, stream>>>(x, node_emb, pre_lin_W, pre_lin_b, h);
    k_hist<<<625, 256, 0, stream>>>(edge_index, cnt);
    k_scan<<<1, 256, 0, stream>>>(cnt, eoff);
    k_nodestats<<<40, 256, 0, stream>>>(cnt, eoff, invdeg, amp, att, cursor);
    k_scatter<<<625, 256, 0, stream>>>(edge_index, edge_attr, cursor, esrc, ecombo);

    for (int l = 0; l < NL; l++){
        k_pq<<<319, 384, 0, stream>>>(h, hc, bng, bnb, preW, preb, edge_emb,
                                      encW, encb, l, P, Q, Rlut, stats);
        k_agg<<<dim3(6, NN), 64, 0, stream>>>(P, Q, Rlut, eoff, esrc, ecombo, invdeg, agg);
        k_post<<<dim3(40, 5, 7), 256, 0, stream>>>(h, agg, postW, postb, amp, att, l, postbase);
        k_lin<<<157, 256, 0, stream>>>(postbase, linW, linb, l, hc, stats);
    }

    // final BN (layer 3) -> h, then pool + MLP
    k_bnapply<<<2930, 256, 0, stream>>>(hc, stats + ((NL-1)&1)*192, bng, bnb, NL-1, h);
    k_pool<<<NG, 256, 0, stream>>>(h, batch, gpool);
    k_mlp<<<8, 256, 0, stream>>>(gpool, mlpW1, mlpb1, mlpW2, mlpb2, mlpW3, mlpb3, (float*)d_out);
}

// Round 18
// 908.729 us; speedup vs baseline: 1.0405x; 1.0405x over previous
//
#include <hip/hip_runtime.h>
#include <hip/hip_bf16.h>
#include <math.h>

#define NN 10000
#define NE 160000
#define NG 64
#define NT 5
#define NL 4
#define ADL 2.833213344056216f

// ws layout (float offsets)
#define OFF_H      0
#define OFF_HC     750000
#define OFF_P      1500000     // bf16 P during agg; reused as bf16 post partials z=0..6
#define OFF_Q      5250000     // bf16 Q
#define OFF_AGG    9000000     // bf16 agg
#define OFF_RLUT   24000000
#define OFF_INVDEG 24006000
#define OFF_AMP    24016000
#define OFF_ATT    24026000
#define OFF_STATS  24036000    // 2 ping-pong buffers x 192 floats
#define OFF_GPOOL  24040000
#define OFF_INT    24118960

__device__ __forceinline__ float bf2f(__hip_bfloat16 v){ return __bfloat162float(v); }

__global__ void k_zero_cnt(int* cnt){
    int i = blockIdx.x*256 + threadIdx.x;
    if (i < NN) cnt[i] = 0;
}

// h0 = node_emb[x].reshape(N,150) @ pre_lin_W + b
__global__ __launch_bounds__(256) void k_h0(const int* __restrict__ x,
        const float* __restrict__ node_emb, const float* __restrict__ plW,
        const float* __restrict__ plb, float* __restrict__ h){
    __shared__ float s_emb[21*75];
    __shared__ float s_W[150*75];
    __shared__ float s_b[75];
    int tid = threadIdx.x;
    for (int i = tid; i < 21*75; i += 256) s_emb[i] = node_emb[i];
    for (int i = tid; i < 150*75; i += 256) s_W[i] = plW[i];
    if (tid < 75) s_b[tid] = plb[tid];
    __syncthreads();
    for (int out = blockIdx.x*256 + tid; out < NN*75; out += gridDim.x*256){
        int n = out / 75, f = out - n*75;
        int x0 = x[2*n], x1 = x[2*n+1];
        float acc = s_b[f];
        const float* e0 = s_emb + x0*75;
        const float* e1 = s_emb + x1*75;
        #pragma unroll 5
        for (int k = 0; k < 75; k++)
            acc += e0[k]*s_W[k*75+f] + e1[k]*s_W[(75+k)*75+f];
        h[out] = acc;
    }
}

__global__ void k_hist(const int* __restrict__ ei, int* __restrict__ cnt){
    int e = blockIdx.x*256 + threadIdx.x;
    if (e < NE) atomicAdd(&cnt[ei[NE + e]], 1);
}

// single-block prefix sum: eoff[0]=0, eoff[n+1]=inclusive prefix
__global__ void k_scan(const int* __restrict__ cnt, int* __restrict__ eoff){
    __shared__ int buf[256];
    __shared__ int carry;
    int tid = threadIdx.x;
    if (tid == 0){ carry = 0; eoff[0] = 0; }
    __syncthreads();
    for (int base = 0; base < NN; base += 256){
        int v = (base + tid < NN) ? cnt[base + tid] : 0;
        buf[tid] = v; __syncthreads();
        for (int off = 1; off < 256; off <<= 1){
            int t2 = (tid >= off) ? buf[tid - off] : 0;
            __syncthreads();
            buf[tid] += t2;
            __syncthreads();
        }
        int inc = buf[tid] + carry;
        if (base + tid < NN) eoff[base + tid + 1] = inc;
        __syncthreads();
        if (tid == 255) carry = inc;
        __syncthreads();
    }
}

__global__ void k_nodestats(const int* __restrict__ cnt, const int* __restrict__ eoff,
        float* __restrict__ invdeg, float* __restrict__ amp, float* __restrict__ att,
        int* __restrict__ cursor){
    int n = blockIdx.x*256 + threadIdx.x;
    if (n >= NN) return;
    int c = cnt[n];
    cursor[n] = eoff[n];
    float cf = (float)c;
    float dg = cf < 1.f ? 1.f : cf;
    invdeg[n] = 1.f / dg;
    float ld = logf(dg + 1.f);
    amp[n] = ld / ADL;
    att[n] = ADL / ld;
}

__global__ void k_scatter(const int* __restrict__ ei, const int* __restrict__ ea,
        int* __restrict__ cursor, int* __restrict__ esrc, int* __restrict__ ecombo){
    int e = blockIdx.x*256 + threadIdx.x;
    if (e >= NE) return;
    int src = ei[e], dst = ei[NE + e];
    int pos = atomicAdd(&cursor[dst], 1);
    esrc[pos] = src;
    ecombo[pos] = ea[2*e]*4 + ea[2*e+1];
}

// Fused kernel, grid 319 x 384:
//  bx <  313 : P/Q (32 nodes/block, bf16). For l>0, the h-staging applies the
//              PREVIOUS layer's BN+ReLU inline (reads hc + stats ping-pong
//              buffer (l-1)&1) and writes h out — replaces k_bnapply launches.
//  bx 313-317: Rlut for tower t = bx-313
//  bx == 318 : zero stats buffer l&1
__global__ __launch_bounds__(384) void k_pq(float* __restrict__ h,
        const float* __restrict__ hc, const float* __restrict__ bng,
        const float* __restrict__ bnb,
        const float* __restrict__ preW, const float* __restrict__ preb,
        const float* __restrict__ edge_emb, const float* __restrict__ encW,
        const float* __restrict__ encb, int l,
        __hip_bfloat16* __restrict__ P, __hip_bfloat16* __restrict__ Q,
        float* __restrict__ Rlut, float* __restrict__ stats_all){
    __shared__ float smem[10675];
    int tid = threadIdx.x;
    int bx = blockIdx.x;

    if (bx == 318){
        float* stats_wr = stats_all + (l & 1)*192;
        for (int i = tid; i < 150; i += 384) stats_wr[i] = 0.f;
        return;
    }
    if (bx >= 313){
        // ---- Rlut for tower t ----
        int t = bx - 313;
        float* s_encW = smem;            // 50*75 = 3750
        float* s_ev   = smem + 3750;     // 16*75 = 1200
        float* s_wc   = smem + 4950;     // 75*75 = 5625
        float* s_ee   = smem + 10575;    // 100
        for (int i = tid; i < 3750; i += 384) s_encW[i] = encW[(size_t)l*3750 + i];
        for (int i = tid; i < 100; i += 384) s_ee[i] = edge_emb[i];
        const float* wcsrc = preW + (((size_t)(l*NT + t))*225 + 150)*75;
        for (int i = tid; i < 5625; i += 384) s_wc[i] = wcsrc[i];
        __syncthreads();
        for (int task = tid; task < 1200; task += 384){
            int b = task/75, m = task - 75*b;
            int a0 = b >> 2, a1 = b & 3;
            float s = encb[l*75 + m];
            for (int k = 0; k < 25; k++)
                s += s_ee[a0*25+k]*s_encW[k*75+m] + s_ee[a1*25+k]*s_encW[(25+k)*75+m];
            s_ev[task] = s;
        }
        __syncthreads();
        for (int task = tid; task < 1200; task += 384){
            int b = task/75, f = task - 75*b;
            float r = preb[((size_t)l*NT + t)*75 + f];
            const float* ev = s_ev + b*75;
            #pragma unroll 5
            for (int m = 0; m < 75; m++) r += ev[m]*s_wc[m*75 + f];
            Rlut[b*375 + t*75 + f] = r;
        }
        return;
    }

    // ---- P/Q (with inline BN+ReLU from previous layer when l>0) ----
    float* h_t = smem;   // 32*76 = 2432
    int base = bx*32;
    if (l == 0){
        for (int idx = tid; idx < 32*75; idx += 384){
            int i = idx/75, m = idx - 75*i;
            int n = base + i;
            h_t[i*76 + m] = (n < NN) ? h[(size_t)n*75 + m] : 0.f;
        }
    } else {
        const float* stats_rd = stats_all + ((l + 1) & 1)*192;
        int lp = l - 1;
        for (int idx = tid; idx < 32*75; idx += 384){
            int i = idx/75, m = idx - 75*i;
            int n = base + i;
            float v = 0.f;
            if (n < NN){
                float mu = stats_rd[m]*(1.0f/NN);
                float var = stats_rd[75+m]*(1.0f/NN) - mu*mu;
                float inv = rsqrtf(var + 1e-5f);
                v = (hc[(size_t)n*75 + m] - mu)*inv*bng[lp*75+m] + bnb[lp*75+m];
                v = v > 0.f ? v : 0.f;
                h[(size_t)n*75 + m] = v;
            }
            h_t[i*76 + m] = v;
        }
    }
    __syncthreads();
    int j = tid;
    if (j >= 375) return;
    int t = j/75, f = j - 75*t;
    const float* wbase = preW + ((size_t)(l*NT + t))*225*75 + f;
    float accP[32], accQ[32];
    #pragma unroll
    for (int i = 0; i < 32; i++){ accP[i] = 0.f; accQ[i] = 0.f; }
    for (int m = 0; m < 72; m += 4){
        float wa0 = wbase[(m+0)*75], wa1 = wbase[(m+1)*75];
        float wa2 = wbase[(m+2)*75], wa3 = wbase[(m+3)*75];
        float wb0 = wbase[(75+m+0)*75], wb1 = wbase[(75+m+1)*75];
        float wb2 = wbase[(75+m+2)*75], wb3 = wbase[(75+m+3)*75];
        #pragma unroll
        for (int i = 0; i < 32; i++){
            const float4 hv = *(const float4*)&h_t[i*76 + m];
            accP[i] += hv.x*wa0 + hv.y*wa1 + hv.z*wa2 + hv.w*wa3;
            accQ[i] += hv.x*wb0 + hv.y*wb1 + hv.z*wb2 + hv.w*wb3;
        }
    }
    for (int m = 72; m < 75; m++){
        float wa = wbase[m*75], wb = wbase[(75+m)*75];
        #pragma unroll
        for (int i = 0; i < 32; i++){
            float v = h_t[i*76 + m];
            accP[i] += v*wa; accQ[i] += v*wb;
        }
    }
    for (int i = 0; i < 32; i++){
        int n = base + i;
        if (n < NN){
            P[(size_t)n*375 + j] = __float2bfloat16(accP[i]);
            Q[(size_t)n*375 + j] = __float2bfloat16(accQ[i]);
        }
    }
}

// grid (6, NN), block 64. bf16 Q gather; edge loop unrolled x8.
__global__ __launch_bounds__(64) void k_agg(const __hip_bfloat16* __restrict__ P,
        const __hip_bfloat16* __restrict__ Q, const float* __restrict__ Rlut,
        const int* __restrict__ eoff, const int* __restrict__ esrc,
        const int* __restrict__ ecombo, const float* __restrict__ invdeg,
        __hip_bfloat16* __restrict__ agg){
    int n = blockIdx.y;
    int j = blockIdx.x*64 + threadIdx.x;
    if (j >= 375) return;
    int lo = eoff[n], hi = eoff[n+1];
    float p = bf2f(P[(size_t)n*375 + j]);
    float sum = 0.f, sq = 0.f, mn = 3.4e38f, mx = -3.4e38f;
    int e = lo;
    for (; e + 8 <= hi; e += 8){
        int s0 = esrc[e],   s1 = esrc[e+1], s2 = esrc[e+2], s3 = esrc[e+3];
        int s4 = esrc[e+4], s5 = esrc[e+5], s6 = esrc[e+6], s7 = esrc[e+7];
        int c0 = ecombo[e],   c1 = ecombo[e+1], c2 = ecombo[e+2], c3 = ecombo[e+3];
        int c4 = ecombo[e+4], c5 = ecombo[e+5], c6 = ecombo[e+6], c7 = ecombo[e+7];
        float q0 = bf2f(Q[(size_t)s0*375 + j]);
        float q1 = bf2f(Q[(size_t)s1*375 + j]);
        float q2 = bf2f(Q[(size_t)s2*375 + j]);
        float q3 = bf2f(Q[(size_t)s3*375 + j]);
        float q4 = bf2f(Q[(size_t)s4*375 + j]);
        float q5 = bf2f(Q[(size_t)s5*375 + j]);
        float q6 = bf2f(Q[(size_t)s6*375 + j]);
        float q7 = bf2f(Q[(size_t)s7*375 + j]);
        float r0 = Rlut[c0*375 + j], r1 = Rlut[c1*375 + j];
        float r2 = Rlut[c2*375 + j], r3 = Rlut[c3*375 + j];
        float r4 = Rlut[c4*375 + j], r5 = Rlut[c5*375 + j];
        float r6 = Rlut[c6*375 + j], r7 = Rlut[c7*375 + j];
        float m0 = p + q0 + r0, m1 = p + q1 + r1;
        float m2 = p + q2 + r2, m3 = p + q3 + r3;
        float m4 = p + q4 + r4, m5 = p + q5 + r5;
        float m6 = p + q6 + r6, m7 = p + q7 + r7;
        sum += (m0 + m1 + m2 + m3) + (m4 + m5 + m6 + m7);
        sq  += (m0*m0 + m1*m1 + m2*m2 + m3*m3) + (m4*m4 + m5*m5 + m6*m6 + m7*m7);
        mn = fminf(mn, fminf(fminf(fminf(m0,m1), fminf(m2,m3)),
                             fminf(fminf(m4,m5), fminf(m6,m7))));
        mx = fmaxf(mx, fmaxf(fmaxf(fmaxf(m0,m1), fmaxf(m2,m3)),
                             fmaxf(fmaxf(m4,m5), fmaxf(m6,m7))));
    }
    for (; e < hi; e++){
        int s = esrc[e], cm = ecombo[e];
        float m = p + bf2f(Q[(size_t)s*375 + j]) + Rlut[cm*375 + j];
        sum += m; sq += m*m;
        mn = fminf(mn, m); mx = fmaxf(mx, m);
    }
    float id = invdeg[n];
    bool has = hi > lo;
    float mean = sum*id;
    float msq  = sq*id;
    float var = msq - mean*mean; var = var > 0.f ? var : 0.f;
    float sd = sqrtf(var + 1e-5f);
    float mnv = has ? mn : 0.f;
    float mxv = has ? mx : 0.f;
    int t = j/75, f = j - 75*t;
    __hip_bfloat16* a = agg + ((size_t)n*NT + t)*300;
    a[f]      = __float2bfloat16(mean);
    a[75+f]   = __float2bfloat16(mnv);
    a[150+f]  = __float2bfloat16(mxv);
    a[225+f]  = __float2bfloat16(sd);
}

// post einsum, barrier-free; bf16 partials. grid (40, 5, 7).
#define KB2 50
__global__ __launch_bounds__(256, 6) void k_post(const float* __restrict__ h,
        const __hip_bfloat16* __restrict__ agg, const float* __restrict__ postW,
        const float* __restrict__ postb, const float* __restrict__ amp,
        const float* __restrict__ att, int l, __hip_bfloat16* __restrict__ postbase){
    __shared__ float s_w[3*KB2*16];      // 9.6 KB (z0 uses first 75*16=1200)
    int t = blockIdx.y;
    int z = blockIdx.z;
    int nbase = blockIdx.x*256;
    int tid = threadIdx.x;
    int fg  = (tid & 3)*4;
    int sub = tid >> 2;
    const float* Wt = postW + ((size_t)(l*NT + t))*975*15;

    if (z == 0){
        for (int idx = tid; idx < 75*16; idx += 256){
            int c = idx >> 4, f = idx & 15;
            s_w[idx] = (f < 15) ? Wt[c*15 + f] : 0.f;
        }
        __syncthreads();
        float a1[4][4] = {};
        const float* hrow[4];
        #pragma unroll
        for (int j = 0; j < 4; j++){
            int n = nbase + sub + 64*j;
            hrow[j] = h + (size_t)(n < NN ? n : 0)*75;
        }
        #pragma unroll 3
        for (int k = 0; k < 75; k++){
            const float4 w1 = *(const float4*)&s_w[k*16 + fg];
            #pragma unroll
            for (int j = 0; j < 4; j++){
                float v = hrow[j][k];
                a1[j][0] += v*w1.x; a1[j][1] += v*w1.y;
                a1[j][2] += v*w1.z; a1[j][3] += v*w1.w;
            }
        }
        const float* pb = postb + (l*NT + t)*15;
        #pragma unroll
        for (int j = 0; j < 4; j++){
            int n = nbase + sub + 64*j;
            if (n >= NN) continue;
            __hip_bfloat16* dst = postbase + (size_t)n*75 + t*15;
            #pragma unroll
            for (int f = 0; f < 4; f++)
                if (fg + f < 15) dst[fg + f] = __float2bfloat16(a1[j][f] + pb[fg + f]);
        }
        return;
    }

    int kbeg = (z-1)*KB2;
    for (int idx = tid; idx < 3*KB2*16; idx += 256){
        int vrow = idx / (KB2*16);
        int rem = idx - vrow*(KB2*16);
        int c = rem >> 4, f = rem & 15;
        s_w[idx] = (f < 15) ? Wt[(75 + vrow*300 + kbeg + c)*15 + f] : 0.f;
    }
    __syncthreads();
    float a1[4][4] = {}, a2[4][4] = {}, a3[4][4] = {};
    const __hip_bfloat16* arow[4];
    #pragma unroll
    for (int j = 0; j < 4; j++){
        int n = nbase + sub + 64*j;
        arow[j] = agg + (size_t)(n < NN ? n : 0)*1500 + t*300 + kbeg;
    }
    #pragma unroll 2
    for (int k = 0; k < KB2; k++){
        const float4 w1 = *(const float4*)&s_w[k*16 + fg];
        const float4 w2 = *(const float4*)&s_w[(KB2 + k)*16 + fg];
        const float4 w3 = *(const float4*)&s_w[(2*KB2 + k)*16 + fg];
        #pragma unroll
        for (int j = 0; j < 4; j++){
            float v = bf2f(arow[j][k]);
            a1[j][0] += v*w1.x; a1[j][1] += v*w1.y;
            a1[j][2] += v*w1.z; a1[j][3] += v*w1.w;
            a2[j][0] += v*w2.x; a2[j][1] += v*w2.y;
            a2[j][2] += v*w2.z; a2[j][3] += v*w2.w;
            a3[j][0] += v*w3.x; a3[j][1] += v*w3.y;
            a3[j][2] += v*w3.z; a3[j][3] += v*w3.w;
        }
    }
    __hip_bfloat16* postv = postbase + (size_t)z*750000;
    #pragma unroll
    for (int j = 0; j < 4; j++){
        int n = nbase + sub + 64*j;
        if (n >= NN) continue;
        float am = amp[n], at = att[n];
        __hip_bfloat16* dst = postv + (size_t)n*75 + t*15;
        #pragma unroll
        for (int f = 0; f < 4; f++)
            if (fg + f < 15)
                dst[fg + f] = __float2bfloat16(a1[j][f] + am*a2[j][f] + at*a3[j][f]);
    }
}

// hc = (Σz postz) @ lin_W[l] + lin_b[l]; fused BN-stat reduction into buffer l&1.
// 32 nodes/block, 313 blocks (R16 geometry — 157 blocks underfilled 256 CUs).
__global__ __launch_bounds__(256) void k_lin(const __hip_bfloat16* __restrict__ postbase,
        const float* __restrict__ linW, const float* __restrict__ linb,
        int l, float* __restrict__ hc, float* __restrict__ stats_all){
    __shared__ float p_l[32*75];
    __shared__ float w_l[75*75];
    __shared__ float hc_l[32*75];
    int tid = threadIdx.x;
    int base = blockIdx.x*32;
    for (int i = tid; i < 75*75; i += 256) w_l[i] = linW[(size_t)l*5625 + i];
    for (int i = tid; i < 32*75; i += 256){
        int n = base + i/75;
        size_t idx = (size_t)base*75 + i;
        float v = 0.f;
        if (n < NN){
            #pragma unroll
            for (int z = 0; z < 7; z++) v += bf2f(postbase[idx + (size_t)z*750000]);
        }
        p_l[i] = v;
    }
    __syncthreads();
    for (int task = tid; task < 2400; task += 256){
        int i = task/75, o = task - 75*i;
        float s = linb[l*75 + o];
        const float* pl = p_l + i*75;
        #pragma unroll 5
        for (int j = 0; j < 75; j++) s += pl[j]*w_l[j*75 + o];
        hc_l[task] = s;
        if (base + i < NN) hc[(size_t)(base+i)*75 + o] = s;
    }
    __syncthreads();
    if (tid < 75){
        float* stats_wr = stats_all + (l & 1)*192;
        int nv = NN - base; if (nv > 32) nv = 32;
        float s1 = 0.f, s2 = 0.f;
        for (int i = 0; i < nv; i++){
            float v = hc_l[i*75 + tid];
            s1 += v; s2 += v*v;
        }
        atomicAdd(&stats_wr[tid], s1);
        atomicAdd(&stats_wr[75+tid], s2);
    }
}

// final BN apply (only after last layer; earlier layers fused into k_pq)
__global__ void k_bnapply(const float* __restrict__ hc, const float* __restrict__ stats,
        const float* __restrict__ bng, const float* __restrict__ bnb, int l,
        float* __restrict__ h){
    int idx = blockIdx.x*256 + threadIdx.x;
    if (idx >= NN*75) return;
    int col = idx % 75;
    float mu = stats[col]*(1.0f/NN);
    float var = stats[75+col]*(1.0f/NN) - mu*mu;
    float inv = rsqrtf(var + 1e-5f);
    float v = (hc[idx] - mu)*inv*bng[l*75+col] + bnb[l*75+col];
    h[idx] = v > 0.f ? v : 0.f;
}

__global__ __launch_bounds__(256) void k_pool(const float* __restrict__ h,
        const int* __restrict__ batch, float* __restrict__ gpool){
    int g = blockIdx.x, tid = threadIdx.x;
    int lo = 0, hi = NN;
    while (lo < hi){ int mid = (lo+hi)>>1; if (batch[mid] < g) lo = mid+1; else hi = mid; }
    int start = lo;
    lo = start; hi = NN;
    while (lo < hi){ int mid = (lo+hi)>>1; if (batch[mid] < g+1) lo = mid+1; else hi = mid; }
    int end = lo;
    __shared__ float red[225];
    if (tid < 225){
        int col = tid % 75, rep = tid / 75;
        float acc = 0.f;
        for (int i = start + rep; i < end; i += 3) acc += h[(size_t)i*75 + col];
        red[tid] = acc;
    }
    __syncthreads();
    if (tid < 75) gpool[g*75 + tid] = red[tid] + red[75+tid] + red[150+tid];
}

// 8 blocks x 8 graphs; weights in LDS, phase-parallel
__global__ __launch_bounds__(256) void k_mlp(const float* __restrict__ gpool,
        const float* __restrict__ W1, const float* __restrict__ b1,
        const float* __restrict__ W2, const float* __restrict__ b2,
        const float* __restrict__ W3, const float* __restrict__ b3,
        float* __restrict__ out){
    __shared__ float w1[75*50];
    __shared__ float w2[50*25];
    __shared__ float gp[8*75];
    __shared__ float t1[8*50];
    __shared__ float t2[8*25];
    int tid = threadIdx.x;
    int gbase = blockIdx.x*8;
    for (int i = tid; i < 75*50; i += 256) w1[i] = W1[i];
    for (int i = tid; i < 50*25; i += 256) w2[i] = W2[i];
    for (int i = tid; i < 8*75; i += 256) gp[i] = gpool[gbase*75 + i];
    __syncthreads();
    for (int task = tid; task < 8*50; task += 256){
        int g = task/50, j = task - 50*g;
        float s = b1[j];
        const float* gv = gp + g*75;
        #pragma unroll 5
        for (int k = 0; k < 75; k++) s += gv[k]*w1[k*50+j];
        t1[task] = s > 0.f ? s : 0.f;
    }
    __syncthreads();
    for (int task = tid; task < 8*25; task += 256){
        int g = task/25, j = task - 25*g;
        float s = b2[j];
        const float* tv = t1 + g*50;
        #pragma unroll 5
        for (int k = 0; k < 50; k++) s += tv[k]*w2[k*25+j];
        t2[task] = s > 0.f ? s : 0.f;
    }
    __syncthreads();
    if (tid < 8){
        float s = b3[0];
        const float* tv = t2 + tid*25;
        #pragma unroll
        for (int k = 0; k < 25; k++) s += tv[k]*W3[k];
        out[gbase + tid] = s;
    }
}

extern "C" void kernel_launch(void* const* d_in, const int* in_sizes, int n_in,
                              void* d_out, int out_size, void* d_ws, size_t ws_size,
                              hipStream_t stream){
    const int* x          = (const int*)d_in[0];
    const int* edge_index = (const int*)d_in[1];
    const int* edge_attr  = (const int*)d_in[2];
    const int* batch      = (const int*)d_in[3];
    const float* node_emb = (const float*)d_in[4];
    const float* edge_emb = (const float*)d_in[5];
    const float* pre_lin_W= (const float*)d_in[6];
    const float* pre_lin_b= (const float*)d_in[7];
    const float* encW     = (const float*)d_in[8];
    const float* encb     = (const float*)d_in[9];
    const float* preW     = (const float*)d_in[10];
    const float* preb     = (const float*)d_in[11];
    const float* postW    = (const float*)d_in[12];
    const float* postb    = (const float*)d_in[13];
    const float* linW     = (const float*)d_in[14];
    const float* linb     = (const float*)d_in[15];
    const float* bng      = (const float*)d_in[16];
    const float* bnb      = (const float*)d_in[17];
    const float* mlpW1    = (const float*)d_in[18];
    const float* mlpb1    = (const float*)d_in[19];
    const float* mlpW2    = (const float*)d_in[20];
    const float* mlpb2    = (const float*)d_in[21];
    const float* mlpW3    = (const float*)d_in[22];
    const float* mlpb3    = (const float*)d_in[23];

    float* ws = (float*)d_ws;
    float* h      = ws + OFF_H;
    float* hc     = ws + OFF_HC;
    __hip_bfloat16* P = (__hip_bfloat16*)(ws + OFF_P);
    __hip_bfloat16* Q = (__hip_bfloat16*)(ws + OFF_Q);
    __hip_bfloat16* agg = (__hip_bfloat16*)(ws + OFF_AGG);
    float* Rlut   = ws + OFF_RLUT;
    float* invdeg = ws + OFF_INVDEG;
    float* amp    = ws + OFF_AMP;
    float* att    = ws + OFF_ATT;
    float* stats  = ws + OFF_STATS;   // 2 x 192 ping-pong
    float* gpool  = ws + OFF_GPOOL;
    __hip_bfloat16* postbase = (__hip_bfloat16*)(ws + OFF_P);  // bf16 partials z=0..6
    int* iw     = (int*)(ws + OFF_INT);
    int* cnt    = iw;
    int* eoff   = cnt + NN;        // NN+1
    int* cursor = eoff + NN + 2;
    int* esrc   = cursor + NN;
    int* ecombo = esrc + NE;

    k_zero_cnt<<<40, 256, 0, stream>>>(cnt);
    k_h0<<<640, 256, 0, stream>>>(x, node_emb, pre_lin_W, pre_lin_b, h);
    k_hist<<<625, 256, 0, stream>>>(edge_index, cnt);
    k_scan<<<1, 256, 0, stream>>>(cnt, eoff);
    k_nodestats<<<40, 256, 0, stream>>>(cnt, eoff, invdeg, amp, att, cursor);
    k_scatter<<<625, 256, 0, stream>>>(edge_index, edge_attr, cursor, esrc, ecombo);

    for (int l = 0; l < NL; l++){
        k_pq<<<319, 384, 0, stream>>>(h, hc, bng, bnb, preW, preb, edge_emb,
                                      encW, encb, l, P, Q, Rlut, stats);
        k_agg<<<dim3(6, NN), 64, 0, stream>>>(P, Q, Rlut, eoff, esrc, ecombo, invdeg, agg);
        k_post<<<dim3(40, 5, 7), 256, 0, stream>>>(h, agg, postW, postb, amp, att, l, postbase);
        k_lin<<<313, 256, 0, stream>>>(postbase, linW, linb, l, hc, stats);
    }

    // final BN (layer 3) -> h, then pool + MLP
    k_bnapply<<<2930, 256, 0, stream>>>(hc, stats + ((NL-1)&1)*192, bng, bnb, NL-1, h);
    k_pool<<<NG, 256, 0, stream>>>(h, batch, gpool);
    k_mlp<<<8, 256, 0, stream>>>(gpool, mlpW1, mlpb1, mlpW2, mlpb2, mlpW3, mlpb3, (float*)d_out);
}